// Round 13
// baseline (307.013 us; speedup 1.0000x reference)
//
#include <hip/hip_runtime.h>

typedef float v4f __attribute__((ext_vector_type(4)));

#define NB   32     // batch
#define NT   8      // timesteps
#define NC   128    // channels
#define NQ   256    // float4s per (H*W)=1024 plane
#define CRED 32     // C/red

// Cross-block mean publish: word = (seq<<32) | 32-bit-half-of-double-bits,
// seq = t+1. Data+version share ONE atomic location -> freshness is
// self-validating (R0 lesson). One write-once slice PER STEP -> no WAR
// hazard -> no arrive barrier. Zeroed per launch (seq=0 invalid on replays).
#define NWORDS (NT * NB * NC * 2)   // step x batch x channel x {lo,hi}

__device__ unsigned long long g_xw[NWORDS];          // (seq<<32 | half) words

__global__ __launch_bounds__(256)
void lif_init() {
    int i = threadIdx.x + blockIdx.x * blockDim.x;
    if (i < NWORDS) g_xw[i] = 0ull;
}

// LDS-only barrier: lgkmcnt drain, NO vmcnt(0); bulk stores stay in flight.
#define LDS_BARRIER() asm volatile("s_waitcnt lgkmcnt(0)\n\ts_barrier" ::: "memory")

// ---------------------------------------------------------------------------
// R6: WAVE-SPECIALIZED QUEUES (producer/consumer). Evidence from R3 vs R5
// A/B: the per-wave VMEM queue retires IN ORDER, and the publish is the head
// of the inter-block chain -- any bulk ahead of it delays all 32 consumers
// (R5: +2.9 us/step = store-drain time); any bulk the polling wave must
// drain serializes memory with the sync chain (R3's structural floor).
// Fix: wave 0's queue carries ONLY {publish, poll} -- never bulk.
//   wave 0: phaseA -> sp0->LDS + reset (pre-B1) -> B1 -> publish ->
//           64-lane x 4-word poll (__all retry, 1 RT) -> s_xm -> MLP -> s_tau
//   wave 1: own prefetch + wave-0 prefetch -> own spike/store/reset ->
//           vmcnt(only xv0 loads) -> s_xv0 handoff       (stores in flight)
//   wave 2: own prefetch -> s_sp0 ds_read -> own + wave-0 spike stores
//   wave 3: own prefetch -> own spike/store/reset
// Bulk drains run in the background of the sync chain; bulk waves' next
// waits leave stores outstanding by in-order queue position. 2 barriers/
// step. All arithmetic (fma/psum/reduce/publish bits/MLP order/sigmoid)
// identical -> spikes and tau bit-identical to the verified R3 kernel.
// Co-residency: ~80 VGPR @ (256,4) -> >=4 blocks/CU for all 1024 blocks;
// spins cannot deadlock. WAR on s_xv0/s_sp0/s_part separated by B1/B2.
// ---------------------------------------------------------------------------
__global__ __launch_bounds__(256, 4)
void dynamic_lif(const float* __restrict__ x,
                 const float* __restrict__ w1,
                 const float* __restrict__ b1,
                 const float* __restrict__ w2,
                 const float* __restrict__ b2,
                 float* __restrict__ out)
{
    const int bid = blockIdx.x;          // 0..1023
    const int b   = bid >> 5;            // batch
    const int c0  = (bid & 31) << 2;     // first of 4 channels
    const int tid = threadIdx.x;
    const int wv  = tid >> 6;
    const int ln  = tid & 63;

    __shared__ double             s_part[4][4];
    __shared__ v4f                s_xv0[4][64];  // wave-0 prefetch handoff
    __shared__ v4f                s_sp0[4][64];  // wave-0 spike handoff
    __shared__ unsigned long long s_xm[NC];      // mean bits (wave 0)
    __shared__ float              s_tau;

    const v4f* __restrict__ x4 = (const v4f*)x;
    v4f* __restrict__ o4       = (v4f*)out;

    v4f mem[4];
    #pragma unroll
    for (int p = 0; p < 4; ++p) mem[p] = (v4f){0.f, 0.f, 0.f, 0.f};

    float tau = 0.5f;                    // TAU0

    v4f xv[4];
    #pragma unroll
    for (int p = 0; p < 4; ++p)
        xv[p] = __builtin_nontemporal_load(x4 + ((b * NT + 0) * NC + c0 + p) * NQ + tid);

    for (int t = 0; t < NT; ++t) {
        // wave 0, t>0: xv arrives via LDS handoff (certified by B2 of t-1)
        if (wv == 0 && t > 0) {
            #pragma unroll
            for (int p = 0; p < 4; ++p) xv[p] = s_xv0[p][ln];
        }

        // ---- phase A: fma + plane-sum; mem keeps PRE-reset values ----
        double psum[4];
        #pragma unroll
        for (int p = 0; p < 4; ++p) {
            v4f m = mem[p];
            m.x = fmaf(m.x, tau, xv[p].x);
            m.y = fmaf(m.y, tau, xv[p].y);
            m.z = fmaf(m.z, tau, xv[p].z);
            m.w = fmaf(m.w, tau, xv[p].w);
            psum[p] = ((double)m.x + (double)m.y) + ((double)m.z + (double)m.w);
            mem[p] = m;
        }
        #pragma unroll
        for (int p = 0; p < 4; ++p) {
            double s = psum[p];
            #pragma unroll
            for (int off = 32; off > 0; off >>= 1) s += __shfl_down(s, off);
            if (ln == 0) s_part[p][wv] = s;
        }

        // wave 0: spike handoff + reset BEFORE B1 (VALU+LDS only; B1
        // certifies s_sp0 for wave 2). Wave-0 never global-stores spikes.
        if (t < NT - 1 && wv == 0) {
            #pragma unroll
            for (int p = 0; p < 4; ++p) {
                v4f m = mem[p];
                v4f sp;
                sp.x = (m.x > 1.0f) ? 1.0f : 0.0f;   // zif(mem-1): exact
                sp.y = (m.y > 1.0f) ? 1.0f : 0.0f;
                sp.z = (m.z > 1.0f) ? 1.0f : 0.0f;
                sp.w = (m.w > 1.0f) ? 1.0f : 0.0f;
                s_sp0[p][ln] = sp;
                m.x = (m.x > 1.0f) ? 0.0f : m.x;     // (1-spike)*mem
                m.y = (m.y > 1.0f) ? 0.0f : m.y;
                m.z = (m.z > 1.0f) ? 0.0f : m.z;
                m.w = (m.w > 1.0f) ? 0.0f : m.w;
                mem[p] = m;
            }
        }
        LDS_BARRIER();                   // B1: s_part + s_sp0 visible

        if (t == NT - 1) {
            // uniform last step: every wave stores its own spikes
            #pragma unroll
            for (int p = 0; p < 4; ++p) {
                v4f m = mem[p];
                v4f sp;
                sp.x = (m.x > 1.0f) ? 1.0f : 0.0f;
                sp.y = (m.y > 1.0f) ? 1.0f : 0.0f;
                sp.z = (m.z > 1.0f) ? 1.0f : 0.0f;
                sp.w = (m.w > 1.0f) ? 1.0f : 0.0f;
                __builtin_nontemporal_store(sp,
                    o4 + ((b * NT + t) * NC + c0 + p) * NQ + tid);
            }
            break;
        }

        if (wv == 0) {
            // ---- publish: the ONLY stores ever in wave-0's queue ----
            if (ln < 4) {
                double s = (s_part[ln][0] + s_part[ln][1]) +
                           (s_part[ln][2] + s_part[ln][3]);
                double mean = s * (1.0 / 1024.0);
                unsigned long long bits = __double_as_longlong(mean);
                unsigned long long tag  = ((unsigned long long)(t + 1)) << 32;
                const int base = ((t * NB + b) * NC + c0 + ln) * 2;
                __hip_atomic_store(&g_xw[base + 0], tag | (bits & 0xffffffffull),
                                   __ATOMIC_RELAXED, __HIP_MEMORY_SCOPE_AGENT);
                __hip_atomic_store(&g_xw[base + 1], tag | (bits >> 32),
                                   __ATOMIC_RELAXED, __HIP_MEMORY_SCOPE_AGENT);
            }
            // ---- poll: 4 contiguous words/lane, one RT per iteration,
            // wave-uniform __all retry (no serial spins, no bulk drain) ----
            {
                const unsigned long long* wp =
                    g_xw + (t * NB + b) * NC * 2 + 4 * ln;
                const unsigned int want = (unsigned int)(t + 1);
                unsigned long long a0, a1, a2, a3;
                for (;;) {
                    a0 = __hip_atomic_load(wp + 0, __ATOMIC_RELAXED,
                                           __HIP_MEMORY_SCOPE_AGENT);
                    a1 = __hip_atomic_load(wp + 1, __ATOMIC_RELAXED,
                                           __HIP_MEMORY_SCOPE_AGENT);
                    a2 = __hip_atomic_load(wp + 2, __ATOMIC_RELAXED,
                                           __HIP_MEMORY_SCOPE_AGENT);
                    a3 = __hip_atomic_load(wp + 3, __ATOMIC_RELAXED,
                                           __HIP_MEMORY_SCOPE_AGENT);
                    bool ok = ((unsigned int)(a0 >> 32) == want) &
                              ((unsigned int)(a1 >> 32) == want) &
                              ((unsigned int)(a2 >> 32) == want) &
                              ((unsigned int)(a3 >> 32) == want);
                    if (__all(ok)) break;
                    __builtin_amdgcn_s_sleep(1);
                }
                // lane ln owns channels 2ln, 2ln+1; exact double bits
                s_xm[2 * ln]     = (a1 << 32) | (a0 & 0xffffffffull);
                s_xm[2 * ln + 1] = (a3 << 32) | (a2 & 0xffffffffull);
            }
            // tiny MLP (128->32->1) on lanes 0-31; identical cc-ascending
            // order and exact double bits -> tau bit-identical.
            double e = 0.0;
            if (ln < CRED) {
                const v4f* __restrict__ w1v = (const v4f*)(w1 + ln * NC);
                double acc = (double)b1[ln];
                #pragma unroll
                for (int q = 0; q < NC / 4; ++q) {
                    v4f wq = w1v[q];
                    #pragma unroll
                    for (int k = 0; k < 4; ++k) {
                        const int c = 4 * q + k;
                        double xm = __longlong_as_double(s_xm[c]);
                        acc += xm * (double)((k == 0) ? wq.x : (k == 1) ? wq.y
                                             : (k == 2) ? wq.z : wq.w);
                    }
                }
                double emb = acc > 0.0 ? acc : 0.0;
                e = emb * (double)w2[ln];
            }
            #pragma unroll
            for (int off = 32; off > 0; off >>= 1) e += __shfl_down(e, off);
            if (ln == 0) {
                double z = e + (double)b2[0];
                s_tau = (float)(1.0 / (1.0 + exp(-z)));
            }
        } else if (wv == 1) {
            // bulk: own prefetch, wave-0 prefetch, own spike/store/reset,
            // handoff (vmcnt waits only for the xv0 loads; stores in flight)
            #pragma unroll
            for (int p = 0; p < 4; ++p)
                xv[p] = __builtin_nontemporal_load(
                    x4 + ((b * NT + (t + 1)) * NC + c0 + p) * NQ + tid);
            v4f t0[4];
            #pragma unroll
            for (int p = 0; p < 4; ++p)
                t0[p] = __builtin_nontemporal_load(
                    x4 + ((b * NT + (t + 1)) * NC + c0 + p) * NQ + ln);
            #pragma unroll
            for (int p = 0; p < 4; ++p) {
                v4f m = mem[p];
                v4f sp;
                sp.x = (m.x > 1.0f) ? 1.0f : 0.0f;
                sp.y = (m.y > 1.0f) ? 1.0f : 0.0f;
                sp.z = (m.z > 1.0f) ? 1.0f : 0.0f;
                sp.w = (m.w > 1.0f) ? 1.0f : 0.0f;
                __builtin_nontemporal_store(sp,
                    o4 + ((b * NT + t) * NC + c0 + p) * NQ + tid);
                m.x = (m.x > 1.0f) ? 0.0f : m.x;
                m.y = (m.y > 1.0f) ? 0.0f : m.y;
                m.z = (m.z > 1.0f) ? 0.0f : m.z;
                m.w = (m.w > 1.0f) ? 0.0f : m.w;
                mem[p] = m;
            }
            #pragma unroll
            for (int p = 0; p < 4; ++p) s_xv0[p][ln] = t0[p];
        } else if (wv == 2) {
            // bulk: own prefetch, own spike/store/reset + wave-0 spike stores
            #pragma unroll
            for (int p = 0; p < 4; ++p)
                xv[p] = __builtin_nontemporal_load(
                    x4 + ((b * NT + (t + 1)) * NC + c0 + p) * NQ + tid);
            v4f sp0[4];
            #pragma unroll
            for (int p = 0; p < 4; ++p) sp0[p] = s_sp0[p][ln];
            #pragma unroll
            for (int p = 0; p < 4; ++p) {
                v4f m = mem[p];
                v4f sp;
                sp.x = (m.x > 1.0f) ? 1.0f : 0.0f;
                sp.y = (m.y > 1.0f) ? 1.0f : 0.0f;
                sp.z = (m.z > 1.0f) ? 1.0f : 0.0f;
                sp.w = (m.w > 1.0f) ? 1.0f : 0.0f;
                __builtin_nontemporal_store(sp,
                    o4 + ((b * NT + t) * NC + c0 + p) * NQ + tid);
                m.x = (m.x > 1.0f) ? 0.0f : m.x;
                m.y = (m.y > 1.0f) ? 0.0f : m.y;
                m.z = (m.z > 1.0f) ? 0.0f : m.z;
                m.w = (m.w > 1.0f) ? 0.0f : m.w;
                mem[p] = m;
            }
            #pragma unroll
            for (int p = 0; p < 4; ++p)
                __builtin_nontemporal_store(sp0[p],
                    o4 + ((b * NT + t) * NC + c0 + p) * NQ + ln);
        } else {
            // bulk: own prefetch + own spike/store/reset
            #pragma unroll
            for (int p = 0; p < 4; ++p)
                xv[p] = __builtin_nontemporal_load(
                    x4 + ((b * NT + (t + 1)) * NC + c0 + p) * NQ + tid);
            #pragma unroll
            for (int p = 0; p < 4; ++p) {
                v4f m = mem[p];
                v4f sp;
                sp.x = (m.x > 1.0f) ? 1.0f : 0.0f;
                sp.y = (m.y > 1.0f) ? 1.0f : 0.0f;
                sp.z = (m.z > 1.0f) ? 1.0f : 0.0f;
                sp.w = (m.w > 1.0f) ? 1.0f : 0.0f;
                __builtin_nontemporal_store(sp,
                    o4 + ((b * NT + t) * NC + c0 + p) * NQ + tid);
                m.x = (m.x > 1.0f) ? 0.0f : m.x;
                m.y = (m.y > 1.0f) ? 0.0f : m.y;
                m.z = (m.z > 1.0f) ? 0.0f : m.z;
                m.w = (m.w > 1.0f) ? 0.0f : m.w;
                mem[p] = m;
            }
        }

        LDS_BARRIER();                   // B2: s_tau + s_xv0 certified
        tau = s_tau;
    }
}

extern "C" void kernel_launch(void* const* d_in, const int* in_sizes, int n_in,
                              void* d_out, int out_size, void* d_ws, size_t ws_size,
                              hipStream_t stream) {
    const float* x  = (const float*)d_in[0];
    const float* w1 = (const float*)d_in[1];
    const float* b1 = (const float*)d_in[2];
    const float* w2 = (const float*)d_in[3];
    const float* b2 = (const float*)d_in[4];
    float* out      = (float*)d_out;

    // zero the seq-tagged word buffer (stream-ordered before the main kernel)
    hipLaunchKernelGGL(lif_init, dim3((NWORDS + 255) / 256), dim3(256),
                       0, stream);
    // plain launch — no cooperative protocol overhead
    hipLaunchKernelGGL(dynamic_lif, dim3(NB * NC / 4), dim3(256), 0, stream,
                       x, w1, b1, w2, b2, out);
}

// Round 15
// 272.258 us; speedup vs baseline: 1.1277x; 1.1277x over previous
//
#include <hip/hip_runtime.h>

typedef float v4f __attribute__((ext_vector_type(4)));

#define NB   32     // batch
#define NT   8      // timesteps
#define NC   128    // channels
#define NQ   256    // float4s per (H*W)=1024 plane
#define CRED 32     // C/red

// Cross-block mean publish: each channel mean (double) is split into two
// 64-bit words:  word = (seq << 32) | 32-bit-half-of-double-bits, seq = t+1.
// Data and version share ONE atomic location -> freshness is self-validating
// (no reliance on store-ack == LLC-complete; that was the R0 failure).
// One buffer slice PER STEP (write-once -> no WAR hazard) -> no arrive
// barrier: consumers spin directly on the data words (the poll IS the
// fetch). Zeroed per launch so seq=0 is invalid across graph replays.
#define NWORDS (NT * NB * NC * 2)   // step x batch x channel x {lo,hi}

__device__ unsigned long long g_xw[NWORDS];          // (seq<<32 | half) words

__global__ __launch_bounds__(256)
void lif_init() {
    int i = threadIdx.x + blockIdx.x * blockDim.x;
    if (i < NWORDS) g_xw[i] = 0ull;
}

// Raw barrier: LDS-only drain (lgkmcnt), NO vmcnt(0). Fused into one asm so
// no LDS access can be hoisted between the wait and the barrier. Keeps
// stores fire-and-forget and lets prefetch loads stay in flight.
#define LDS_BARRIER() asm volatile("s_waitcnt lgkmcnt(0)\n\ts_barrier" ::: "memory")

// ---------------------------------------------------------------------------
// R7 = R3 structure (the best measured: 89.1 us) + ONE change: spike stores
// are TEMPORAL (plain), not nontemporal.
// Evidence: R3/R4/R5/R6 A/Bs showed every structural reshuffle of the
// publish/poll/store order regresses; the surviving fact is that NT
// store-acks stay outstanding for multi-us (R5: stores still unretired a
// full sync-chain later => +2.9 us/step). R3's poll drains its own 16 KB of
// spike stores via in-order vmcnt(0); with NT stores that drain waits on
// the memory path. Temporal stores retire at the L2 coherence point
// (sub-us for 16 KB), so the poll's drain collapses; HBM writeback happens
// in the background off any wait path. Watched risk: spike writes now
// traverse L2/L3 and may evict L3-resident x -> FETCH_SIZE rises.
// Step order (unchanged from R3):
//   phase A -> B1 -> publish (first VMEM) -> prefetch + spike/store/reset
//   -> poll (drains L2-acked stores + needed prefetch only) -> B2 -> MLP -> B3.
// fma/psum/reduce/publish-bits/MLP-order/sigmoid untouched -> spikes and
// tau bit-identical to the harness-verified R3 kernel.
// Co-residency: ~56 VGPR @ (256,4) -> 8 blocks/CU capacity, 4 needed; all
// 1024 blocks resident; spin cannot deadlock.
// ---------------------------------------------------------------------------
__global__ __launch_bounds__(256, 4)
void dynamic_lif(const float* __restrict__ x,
                 const float* __restrict__ w1,
                 const float* __restrict__ b1,
                 const float* __restrict__ w2,
                 const float* __restrict__ b2,
                 float* __restrict__ out)
{
    const int bid = blockIdx.x;          // 0..1023
    const int b   = bid >> 5;            // batch
    const int c0  = (bid & 31) << 2;     // first of 4 channels
    const int tid = threadIdx.x;
    const int wv  = tid >> 6;
    const int ln  = tid & 63;

    __shared__ double       s_part[4][4];
    __shared__ unsigned int s_w[256];    // fetched 32-bit halves
    __shared__ float        s_tau;

    const v4f* __restrict__ x4 = (const v4f*)x;
    v4f* __restrict__ o4       = (v4f*)out;

    v4f mem[4];
    #pragma unroll
    for (int p = 0; p < 4; ++p) mem[p] = (v4f){0.f, 0.f, 0.f, 0.f};

    float tau = 0.5f;                    // TAU0

    v4f xv[4];
    #pragma unroll
    for (int p = 0; p < 4; ++p)
        xv[p] = __builtin_nontemporal_load(x4 + ((b * NT + 0) * NC + c0 + p) * NQ + tid);

    for (int t = 0; t < NT; ++t) {
        // ---- phase A: fma + plane-sum ONLY; mem keeps PRE-reset values ----
        double psum[4];
        #pragma unroll
        for (int p = 0; p < 4; ++p) {
            v4f m = mem[p];
            m.x = fmaf(m.x, tau, xv[p].x);
            m.y = fmaf(m.y, tau, xv[p].y);
            m.z = fmaf(m.z, tau, xv[p].z);
            m.w = fmaf(m.w, tau, xv[p].w);
            psum[p] = ((double)m.x + (double)m.y) + ((double)m.z + (double)m.w);
            mem[p] = m;
        }

        #pragma unroll
        for (int p = 0; p < 4; ++p) {
            double s = psum[p];
            #pragma unroll
            for (int off = 32; off > 0; off >>= 1) s += __shfl_down(s, off);
            if (ln == 0) s_part[p][wv] = s;
        }
        LDS_BARRIER();                   // B1: s_part visible to wave 0

        if (t == NT - 1) {
            // last step: nothing consumes the means; just emit spikes
            #pragma unroll
            for (int p = 0; p < 4; ++p) {
                v4f m = mem[p];
                v4f sp;
                sp.x = (m.x > 1.0f) ? 1.0f : 0.0f;   // zif(mem-1): exact
                sp.y = (m.y > 1.0f) ? 1.0f : 0.0f;
                sp.z = (m.z > 1.0f) ? 1.0f : 0.0f;
                sp.w = (m.w > 1.0f) ? 1.0f : 0.0f;
                o4[((b * NT + t) * NC + c0 + p) * NQ + tid] = sp;  // temporal
            }
            break;
        }

        // ---- publish: FIRST VMEM ops of this step for wave 0 ----
        if (tid < 4) {
            double s = (s_part[tid][0] + s_part[tid][1]) +
                       (s_part[tid][2] + s_part[tid][3]);
            double mean = s * (1.0 / 1024.0);
            unsigned long long bits = __double_as_longlong(mean);
            unsigned long long tag  = ((unsigned long long)(t + 1)) << 32;
            const int base = ((t * NB + b) * NC + c0 + tid) * 2;
            // LLC-direct, fire-and-forget; seq tag self-validates freshness
            __hip_atomic_store(&g_xw[base + 0], tag | (bits & 0xffffffffull),
                               __ATOMIC_RELAXED, __HIP_MEMORY_SCOPE_AGENT);
            __hip_atomic_store(&g_xw[base + 1], tag | (bits >> 32),
                               __ATOMIC_RELAXED, __HIP_MEMORY_SCOPE_AGENT);
        }

        // ---- phase B: prefetch, spike, TEMPORAL store, reset ----
        // Store-acks retire at L2 (coherence point), so the poll's vmcnt(0)
        // drain below is cheap; HBM writeback proceeds in the background.
        if (t + 1 < NT) {
            #pragma unroll
            for (int p = 0; p < 4; ++p)
                xv[p] = __builtin_nontemporal_load(
                    x4 + ((b * NT + (t + 1)) * NC + c0 + p) * NQ + tid);
        }
        #pragma unroll
        for (int p = 0; p < 4; ++p) {
            v4f m = mem[p];
            v4f sp;
            sp.x = (m.x > 1.0f) ? 1.0f : 0.0f;   // zif(mem-1): exact (Sterbenz)
            sp.y = (m.y > 1.0f) ? 1.0f : 0.0f;
            sp.z = (m.z > 1.0f) ? 1.0f : 0.0f;
            sp.w = (m.w > 1.0f) ? 1.0f : 0.0f;
            o4[((b * NT + t) * NC + c0 + p) * NQ + tid] = sp;  // temporal
            m.x = (m.x > 1.0f) ? 0.0f : m.x;     // (1-spike)*mem
            m.y = (m.y > 1.0f) ? 0.0f : m.y;
            m.z = (m.z > 1.0f) ? 0.0f : m.z;
            m.w = (m.w > 1.0f) ? 0.0f : m.w;
            mem[p] = m;
        }

        // ---- seq-validated spin-fetch: the poll IS the fetch ----
        // lane tid -> word (channel tid>>1, half tid&1); spin until the
        // word's embedded seq == t+1, then stash the 32-bit half in LDS.
        {
            const int idx = ((t * NB + b) * NC + (tid >> 1)) * 2 + (tid & 1);
            const unsigned int want = (unsigned int)(t + 1);
            unsigned long long w;
            for (;;) {
                w = __hip_atomic_load(&g_xw[idx], __ATOMIC_RELAXED,
                                      __HIP_MEMORY_SCOPE_AGENT);
                if ((unsigned int)(w >> 32) == want) break;
                __builtin_amdgcn_s_sleep(1);
            }
            s_w[tid] = (unsigned int)w;
        }
        LDS_BARRIER();                   // B2: s_w visible to wave 0

        // tiny MLP (128->32->1), recomputed per block for its own batch.
        // s_w reads are same-address broadcasts (no bank conflicts); w1 row
        // is per-lane contiguous float4 (L1-resident). Mean double bits are
        // reassembled exactly; summation order identical to the verified
        // kernel: cc = 0..127 ascending.
        double e = 0.0;
        if (tid < CRED) {
            const v4f* __restrict__ w1v = (const v4f*)(w1 + tid * NC);
            double acc = (double)b1[tid];
            #pragma unroll
            for (int q = 0; q < NC / 4; ++q) {
                v4f wq = w1v[q];
                #pragma unroll
                for (int k = 0; k < 4; ++k) {
                    const int c = 4 * q + k;
                    unsigned long long bits =
                        ((unsigned long long)s_w[2 * c + 1] << 32) | s_w[2 * c];
                    double xm = __longlong_as_double(bits);
                    acc += xm * (double)((k == 0) ? wq.x : (k == 1) ? wq.y
                                         : (k == 2) ? wq.z : wq.w);
                }
            }
            double emb = acc > 0.0 ? acc : 0.0;
            e = emb * (double)w2[tid];
        }
        #pragma unroll
        for (int off = 32; off > 0; off >>= 1) e += __shfl_down(e, off);
        if (tid == 0) {
            double z = e + (double)b2[0];
            s_tau = (float)(1.0 / (1.0 + exp(-z)));
        }
        LDS_BARRIER();                   // B3: s_tau visible to all waves
        tau = s_tau;
    }
}

extern "C" void kernel_launch(void* const* d_in, const int* in_sizes, int n_in,
                              void* d_out, int out_size, void* d_ws, size_t ws_size,
                              hipStream_t stream) {
    const float* x  = (const float*)d_in[0];
    const float* w1 = (const float*)d_in[1];
    const float* b1 = (const float*)d_in[2];
    const float* w2 = (const float*)d_in[3];
    const float* b2 = (const float*)d_in[4];
    float* out      = (float*)d_out;

    // zero the seq-tagged word buffer (stream-ordered before the main kernel)
    hipLaunchKernelGGL(lif_init, dim3((NWORDS + 255) / 256), dim3(256),
                       0, stream);
    // plain launch — no cooperative protocol overhead
    hipLaunchKernelGGL(dynamic_lif, dim3(NB * NC / 4), dim3(256), 0, stream,
                       x, w1, b1, w2, b2, out);
}

// Round 17
// 268.253 us; speedup vs baseline: 1.1445x; 1.0149x over previous
//
#include <hip/hip_runtime.h>

typedef float v4f __attribute__((ext_vector_type(4)));

#define NB   32     // batch
#define NT   8      // timesteps
#define NC   128    // channels
#define NQ   256    // float4s per (H*W)=1024 plane
#define CRED 32     // C/red
#define CPB  16     // channels per block (R8: was 4)

// Cross-block mean publish: each channel mean (double) is split into two
// 64-bit words:  word = (seq << 32) | 32-bit-half-of-double-bits, seq = t+1.
// Data and version share ONE atomic location -> freshness is self-validating
// (R0 lesson). One write-once slice PER STEP -> no WAR hazard -> no arrive
// barrier: consumers spin directly on the data words. Zeroed per launch so
// seq=0 is invalid across graph replays.
#define NWORDS (NT * NB * NC * 2)   // step x batch x channel x {lo,hi}

__device__ unsigned long long g_xw[NWORDS];          // (seq<<32 | half) words

__global__ __launch_bounds__(256)
void lif_init() {
    int i = threadIdx.x + blockIdx.x * blockDim.x;
    if (i < NWORDS) g_xw[i] = 0ull;
}

// Raw barrier: LDS-only drain (lgkmcnt), NO vmcnt(0). Keeps NT stores
// fire-and-forget and lets prefetch loads stay in flight across barriers.
#define LDS_BARRIER() asm volatile("s_waitcnt lgkmcnt(0)\n\ts_barrier" ::: "memory")

// ---------------------------------------------------------------------------
// R8: SHRINK THE SYNC FAN-IN 4x. Evidence: R3 (89.1us) beats every intra-step
// reorder (R4 94 / R5 112 / R6 128 / R7 93) -> the poll's drain hides inside
// the sibling-skew window; the residual (~4.5us/step over memory) is the TAIL
// of max-over-32-publishers scattered across 32 CUs. This version keeps R3's
// step order VERBATIM but uses 256 blocks x 1024 threads (16 channels each):
//   - publisher fan-in per batch: 8 instead of 32 (3/4 of the skew becomes
//     intra-block, absorbed by on-CU LDS barriers)
//   - poll traffic 4x lower (256 pollers x 256 words, less LLC contention)
//   - one batch per CU (no cross-batch VALU interference)
// Mapping sub=tid>>8, q=tid&255 makes each 4-wave sub-group exactly
// reproduce an old 256-thread block: same lane->q, same wave partials, same
// ((w0+w1)+(w2+w3)) mean order, same publish bits, same cc-ascending MLP,
// same sigmoid -> spikes and tau BIT-IDENTICAL to the verified R3 kernel.
// NT stores restored (R7's temporal variant regressed).
// Co-residency: 256 blocks over 256 CUs @ ~60 VGPR, 2.5 KB LDS -> all
// resident trivially; spin cannot deadlock. Barriers wave-uniform.
// ---------------------------------------------------------------------------
__global__ __launch_bounds__(1024, 4)
void dynamic_lif(const float* __restrict__ x,
                 const float* __restrict__ w1,
                 const float* __restrict__ b1,
                 const float* __restrict__ w2,
                 const float* __restrict__ b2,
                 float* __restrict__ out)
{
    const int bid = blockIdx.x;          // 0..255
    const int b   = bid >> 3;            // batch
    const int c0  = (bid & 7) << 4;      // first of 16 channels
    const int tid = threadIdx.x;         // 0..1023
    const int sub = tid >> 8;            // sub-group 0..3 (4 channels each)
    const int q   = tid & 255;           // v4f index within plane
    const int wig = (tid >> 6) & 3;      // wave index within sub-group
    const int ln  = tid & 63;

    __shared__ double       s_part[CPB][4];  // [channel][wave-in-group]
    __shared__ unsigned int s_w[256];        // fetched 32-bit halves
    __shared__ float        s_tau;

    const v4f* __restrict__ x4 = (const v4f*)x;
    v4f* __restrict__ o4       = (v4f*)out;

    // this thread's 4 channels: c0 + sub*4 + p
    const int cbase = c0 + (sub << 2);

    v4f mem[4];
    #pragma unroll
    for (int p = 0; p < 4; ++p) mem[p] = (v4f){0.f, 0.f, 0.f, 0.f};

    float tau = 0.5f;                    // TAU0

    v4f xv[4];
    #pragma unroll
    for (int p = 0; p < 4; ++p)
        xv[p] = __builtin_nontemporal_load(x4 + ((b * NT + 0) * NC + cbase + p) * NQ + q);

    for (int t = 0; t < NT; ++t) {
        // ---- phase A: fma + plane-sum ONLY; mem keeps PRE-reset values ----
        double psum[4];
        #pragma unroll
        for (int p = 0; p < 4; ++p) {
            v4f m = mem[p];
            m.x = fmaf(m.x, tau, xv[p].x);
            m.y = fmaf(m.y, tau, xv[p].y);
            m.z = fmaf(m.z, tau, xv[p].z);
            m.w = fmaf(m.w, tau, xv[p].w);
            psum[p] = ((double)m.x + (double)m.y) + ((double)m.z + (double)m.w);
            mem[p] = m;
        }

        #pragma unroll
        for (int p = 0; p < 4; ++p) {
            double s = psum[p];
            #pragma unroll
            for (int off = 32; off > 0; off >>= 1) s += __shfl_down(s, off);
            if (ln == 0) s_part[(sub << 2) + p][wig] = s;
        }
        LDS_BARRIER();                   // B1: s_part visible to wave 0

        if (t == NT - 1) {
            // last step: nothing consumes the means; just emit spikes
            #pragma unroll
            for (int p = 0; p < 4; ++p) {
                v4f m = mem[p];
                v4f sp;
                sp.x = (m.x > 1.0f) ? 1.0f : 0.0f;   // zif(mem-1): exact
                sp.y = (m.y > 1.0f) ? 1.0f : 0.0f;
                sp.z = (m.z > 1.0f) ? 1.0f : 0.0f;
                sp.w = (m.w > 1.0f) ? 1.0f : 0.0f;
                __builtin_nontemporal_store(sp,
                    o4 + ((b * NT + t) * NC + cbase + p) * NQ + q);
            }
            break;
        }

        // ---- publish: FIRST VMEM ops of this step for wave 0 ----
        // tid<16: one channel each; same ((w0+w1)+(w2+w3)) order as verified.
        if (tid < CPB) {
            double s = (s_part[tid][0] + s_part[tid][1]) +
                       (s_part[tid][2] + s_part[tid][3]);
            double mean = s * (1.0 / 1024.0);
            unsigned long long bits = __double_as_longlong(mean);
            unsigned long long tag  = ((unsigned long long)(t + 1)) << 32;
            const int base = ((t * NB + b) * NC + c0 + tid) * 2;
            // LLC-direct, fire-and-forget; seq tag self-validates freshness
            __hip_atomic_store(&g_xw[base + 0], tag | (bits & 0xffffffffull),
                               __ATOMIC_RELAXED, __HIP_MEMORY_SCOPE_AGENT);
            __hip_atomic_store(&g_xw[base + 1], tag | (bits >> 32),
                               __ATOMIC_RELAXED, __HIP_MEMORY_SCOPE_AGENT);
        }

        // ---- phase B: prefetch, spike, NT store, reset (R3 verbatim) ----
        #pragma unroll
        for (int p = 0; p < 4; ++p)
            xv[p] = __builtin_nontemporal_load(
                x4 + ((b * NT + (t + 1)) * NC + cbase + p) * NQ + q);
        #pragma unroll
        for (int p = 0; p < 4; ++p) {
            v4f m = mem[p];
            v4f sp;
            sp.x = (m.x > 1.0f) ? 1.0f : 0.0f;   // zif(mem-1): exact (Sterbenz)
            sp.y = (m.y > 1.0f) ? 1.0f : 0.0f;
            sp.z = (m.z > 1.0f) ? 1.0f : 0.0f;
            sp.w = (m.w > 1.0f) ? 1.0f : 0.0f;
            __builtin_nontemporal_store(sp,
                o4 + ((b * NT + t) * NC + cbase + p) * NQ + q);
            m.x = (m.x > 1.0f) ? 0.0f : m.x;     // (1-spike)*mem
            m.y = (m.y > 1.0f) ? 0.0f : m.y;
            m.z = (m.z > 1.0f) ? 0.0f : m.z;
            m.w = (m.w > 1.0f) ? 0.0f : m.w;
            mem[p] = m;
        }

        // ---- seq-validated spin-fetch: waves 0-3 only (wave-uniform) ----
        // thread tid<256 -> word tid = channel*2 + half; the drain of this
        // wave's prefetch+stores hides inside the sibling-skew wait.
        if (tid < 256) {
            const int idx = (t * NB + b) * NC * 2 + tid;
            const unsigned int want = (unsigned int)(t + 1);
            unsigned long long w;
            for (;;) {
                w = __hip_atomic_load(&g_xw[idx], __ATOMIC_RELAXED,
                                      __HIP_MEMORY_SCOPE_AGENT);
                if ((unsigned int)(w >> 32) == want) break;
                __builtin_amdgcn_s_sleep(1);
            }
            s_w[tid] = (unsigned int)w;
        }
        LDS_BARRIER();                   // B2: s_w visible to wave 0

        // tiny MLP (128->32->1) on lanes 0-31 of wave 0; identical
        // cc-ascending order and exact double bits -> tau bit-identical.
        double e = 0.0;
        if (tid < CRED) {
            const v4f* __restrict__ w1v = (const v4f*)(w1 + tid * NC);
            double acc = (double)b1[tid];
            #pragma unroll
            for (int qq = 0; qq < NC / 4; ++qq) {
                v4f wq = w1v[qq];
                #pragma unroll
                for (int k = 0; k < 4; ++k) {
                    const int c = 4 * qq + k;
                    unsigned long long bits =
                        ((unsigned long long)s_w[2 * c + 1] << 32) | s_w[2 * c];
                    double xm = __longlong_as_double(bits);
                    acc += xm * (double)((k == 0) ? wq.x : (k == 1) ? wq.y
                                         : (k == 2) ? wq.z : wq.w);
                }
            }
            double emb = acc > 0.0 ? acc : 0.0;
            e = emb * (double)w2[tid];
        }
        #pragma unroll
        for (int off = 32; off > 0; off >>= 1) e += __shfl_down(e, off);
        if (tid == 0) {
            double z = e + (double)b2[0];
            s_tau = (float)(1.0 / (1.0 + exp(-z)));
        }
        LDS_BARRIER();                   // B3: s_tau visible to all 16 waves
        tau = s_tau;
    }
}

extern "C" void kernel_launch(void* const* d_in, const int* in_sizes, int n_in,
                              void* d_out, int out_size, void* d_ws, size_t ws_size,
                              hipStream_t stream) {
    const float* x  = (const float*)d_in[0];
    const float* w1 = (const float*)d_in[1];
    const float* b1 = (const float*)d_in[2];
    const float* w2 = (const float*)d_in[3];
    const float* b2 = (const float*)d_in[4];
    float* out      = (float*)d_out;

    // zero the seq-tagged word buffer (stream-ordered before the main kernel)
    hipLaunchKernelGGL(lif_init, dim3((NWORDS + 255) / 256), dim3(256),
                       0, stream);
    // plain launch — 256 blocks x 1024 threads (one per (batch, 16-channel
    // group)); no cooperative protocol overhead
    hipLaunchKernelGGL(dynamic_lif, dim3(NB * NC / CPB), dim3(1024), 0, stream,
                       x, w1, b1, w2, b2, out);
}